// Round 1
// baseline (1243.061 us; speedup 1.0000x reference)
//
#include <hip/hip_runtime.h>

#define N_NODES  100000
#define N_EDGES  1600000
#define N_GRAPHS 512
#define HID      128

// ---------------- CSR build ----------------

__global__ void zero_int(int* __restrict__ p, int n) {
    int i = blockIdx.x * blockDim.x + threadIdx.x;
    if (i < n) p[i] = 0;
}

__global__ void hist_kernel(const int* __restrict__ dst, int* __restrict__ cnt, int e) {
    int i = blockIdx.x * blockDim.x + threadIdx.x;
    if (i < e) atomicAdd(&cnt[dst[i]], 1);
}

__global__ void dinv_kernel(const int* __restrict__ cnt, float* __restrict__ dinv, int n) {
    int i = blockIdx.x * blockDim.x + threadIdx.x;
    if (i < n) dinv[i] = rsqrtf((float)(cnt[i] + 1));   // +1 = self loop, deg>0 always
}

// single-block exclusive scan: each thread owns a contiguous chunk
__global__ void scan_kernel(const int* __restrict__ cnt, int* __restrict__ row_ptr, int n) {
    const int T = 1024;
    __shared__ int ssum[T];
    int t = threadIdx.x;
    int chunk = (n + T - 1) / T;
    int lo = t * chunk;
    int hi = lo + chunk; if (hi > n) hi = n;
    int s = 0;
    for (int i = lo; i < hi; ++i) s += cnt[i];
    ssum[t] = s;
    __syncthreads();
    for (int off = 1; off < T; off <<= 1) {
        int x = (t >= off) ? ssum[t - off] : 0;
        __syncthreads();
        ssum[t] += x;
        __syncthreads();
    }
    int run = ssum[t] - s;   // exclusive prefix of this chunk
    for (int i = lo; i < hi; ++i) { row_ptr[i] = run; run += cnt[i]; }
    if (t == T - 1) row_ptr[n] = ssum[T - 1];
}

__global__ void copy_int(const int* __restrict__ a, int* __restrict__ b, int n) {
    int i = blockIdx.x * blockDim.x + threadIdx.x;
    if (i < n) b[i] = a[i];
}

__global__ void fill_kernel(const int* __restrict__ src, const int* __restrict__ dst,
                            const float* __restrict__ dinv, int* __restrict__ cursor,
                            int* __restrict__ col, float* __restrict__ wn, int e) {
    int i = blockIdx.x * blockDim.x + threadIdx.x;
    if (i >= e) return;
    int s = src[i], d = dst[i];
    int pos = atomicAdd(&cursor[d], 1);
    col[pos] = s;
    wn[pos]  = dinv[s] * dinv[d];
}

// ---------------- aggregation (gather form) ----------------
// one wave (64 lanes) per node; lane holds 2 of 128 feats (float2)
__global__ void agg128_kernel(const float* __restrict__ h, const int* __restrict__ rp,
                              const int* __restrict__ col, const float* __restrict__ wn,
                              const float* __restrict__ dinv, float* __restrict__ out, int n) {
    int gid  = blockIdx.x * blockDim.x + threadIdx.x;
    int v    = gid >> 6;
    int lane = gid & 63;
    if (v >= n) return;
    int s = rp[v], e = rp[v + 1];
    float dv = dinv[v];
    float w0 = dv * dv;
    float2 xv = ((const float2*)(h + (size_t)v * HID))[lane];
    float ax = w0 * xv.x, ay = w0 * xv.y;
    for (int j = s; j < e; ++j) {
        int u = col[j]; float w = wn[j];
        float2 hu = ((const float2*)(h + (size_t)u * HID))[lane];
        ax += w * hu.x; ay += w * hu.y;
    }
    float2 o; o.x = ax; o.y = ay;
    ((float2*)(out + (size_t)v * HID))[lane] = o;
}

// one wave per node, lane = feature (64-dim input aggregation for conv1)
__global__ void agg64_kernel(const float* __restrict__ x, const int* __restrict__ rp,
                             const int* __restrict__ col, const float* __restrict__ wn,
                             const float* __restrict__ dinv, float* __restrict__ out, int n) {
    int gid  = blockIdx.x * blockDim.x + threadIdx.x;
    int v    = gid >> 6;
    int lane = gid & 63;
    if (v >= n) return;
    int s = rp[v], e = rp[v + 1];
    float dv = dinv[v];
    float acc = dv * dv * x[(size_t)v * 64 + lane];
    for (int j = s; j < e; ++j) {
        acc += wn[j] * x[(size_t)col[j] * 64 + lane];
    }
    out[(size_t)v * 64 + lane] = acc;
}

// ---------------- dense GEMM: out[n,128] = epilogue(A[n,K] @ W[K,128]) ----------------
// epilogue: y = relu(x + bias); if (addend) y += addend[row]
// in-place safe (A tile staged to LDS before any write)
template <int K>
__global__ __launch_bounds__(256)
void gemm_kernel(const float* __restrict__ A, const float* __restrict__ W,
                 const float* __restrict__ bias, const float* __restrict__ addend,
                 float* __restrict__ out, int n) {
    __shared__ float sW[K * 128];
    __shared__ float sA[32 * K];
    int t = threadIdx.x;
    // stage W (K x 128)
    for (int i = t * 4; i < K * 128; i += 256 * 4) {
        *(float4*)&sW[i] = *(const float4*)&W[i];
    }
    // stage A tile: rows row0..row0+31 are contiguous in memory
    int row0 = blockIdx.x * 32;
    const float4* asrc = (const float4*)(A + (size_t)row0 * K);
    float4* adst = (float4*)sA;
    for (int i = t; i < 32 * K / 4; i += 256) adst[i] = asrc[i];
    __syncthreads();

    int tx = t & 31;   // output feature group: 4 consecutive feats
    int ty = t >> 5;   // node group: 4 nodes
    float acc[4][4] = {};
    for (int k = 0; k < K; ++k) {
        float4 b = *(float4*)&sW[k * 128 + tx * 4];
#pragma unroll
        for (int i = 0; i < 4; ++i) {
            float a = sA[(ty * 4 + i) * K + k];
            acc[i][0] += a * b.x; acc[i][1] += a * b.y;
            acc[i][2] += a * b.z; acc[i][3] += a * b.w;
        }
    }
    float4 bv = *(const float4*)&bias[tx * 4];
#pragma unroll
    for (int i = 0; i < 4; ++i) {
        int row = row0 + ty * 4 + i;
        float4 o;
        o.x = fmaxf(acc[i][0] + bv.x, 0.0f);
        o.y = fmaxf(acc[i][1] + bv.y, 0.0f);
        o.z = fmaxf(acc[i][2] + bv.z, 0.0f);
        o.w = fmaxf(acc[i][3] + bv.w, 0.0f);
        if (addend) {
            float4 ad = *(const float4*)&addend[(size_t)row * 128 + tx * 4];
            o.x += ad.x; o.y += ad.y; o.z += ad.z; o.w += ad.w;
        }
        *(float4*)&out[(size_t)row * 128 + tx * 4] = o;
    }
}

// ---------------- pooling ----------------

__global__ void boundary_kernel(const int* __restrict__ batch, int* __restrict__ gstart, int n) {
    int i = blockIdx.x * blockDim.x + threadIdx.x;
    if (i >= n) return;
    int b = batch[i];
    int prev = (i == 0) ? -1 : batch[i - 1];
    for (int g = prev + 1; g <= b; ++g) gstart[g] = i;
    if (i == n - 1) {
        for (int g = b + 1; g <= N_GRAPHS; ++g) gstart[g] = n;
    }
}

__global__ void pool_kernel(const float* __restrict__ h, const int* __restrict__ gstart,
                            float* __restrict__ pooled) {
    int g = blockIdx.x;
    int f = threadIdx.x;  // 128
    int s = gstart[g], e = gstart[g + 1];
    float acc = 0.0f;
    for (int i = s; i < e; ++i) acc += h[(size_t)i * HID + f];
    int c = e - s; if (c < 1) c = 1;
    pooled[g * HID + f] = acc / (float)c;
}

__global__ void out_gemm_kernel(const float* __restrict__ pooled, const float* __restrict__ Wo,
                                const float* __restrict__ bo, float* __restrict__ out) {
    int idx = blockIdx.x * blockDim.x + threadIdx.x;  // 512*16
    if (idx >= N_GRAPHS * 16) return;
    int g = idx >> 4, tgt = idx & 15;
    float acc = bo[tgt];
    for (int k = 0; k < HID; ++k) acc += pooled[g * HID + k] * Wo[k * 16 + tgt];
    out[idx] = acc;
}

// ---------------- launch ----------------

extern "C" void kernel_launch(void* const* d_in, const int* in_sizes, int n_in,
                              void* d_out, int out_size, void* d_ws, size_t ws_size,
                              hipStream_t stream) {
    const float* x       = (const float*)d_in[0];
    const int*   ei      = (const int*)d_in[1];       // [2,E]
    const float* temb_in = (const float*)d_in[2];
    const int*   batch   = (const int*)d_in[3];
    const float* Wt      = (const float*)d_in[4];
    const float* bt      = (const float*)d_in[5];
    const float* W1      = (const float*)d_in[6];
    const float* b1      = (const float*)d_in[7];
    const float* Ws      = (const float*)d_in[8];     // [2,128,128]
    const float* bs      = (const float*)d_in[9];     // [2,128]
    const float* Wo      = (const float*)d_in[10];
    const float* bo      = (const float*)d_in[11];
    float* out = (float*)d_out;

    const int N = N_NODES, E = N_EDGES;
    const int* src = ei;
    const int* dst = ei + E;

    char* p = (char*)d_ws;
    auto carve = [&](size_t bytes) -> void* {
        void* r = (void*)p;
        p += (bytes + 255) & ~(size_t)255;
        return r;
    };
    int*   cnt     = (int*)carve((size_t)N * 4);
    float* dinv    = (float*)carve((size_t)N * 4);
    int*   row_ptr = (int*)carve((size_t)(N + 1) * 4);
    int*   cursor  = (int*)carve((size_t)N * 4);
    int*   col     = (int*)carve((size_t)E * 4);
    float* wn      = (float*)carve((size_t)E * 4);
    int*   gstart  = (int*)carve((size_t)(N_GRAPHS + 1) * 4);
    float* pooled  = (float*)carve((size_t)N_GRAPHS * HID * 4);
    float* A64     = (float*)carve((size_t)N * 64 * 4);
    float* H0      = (float*)carve((size_t)N * HID * 4);
    float* H1      = (float*)carve((size_t)N * HID * 4);

    // --- CSR build ---
    zero_int<<<(N + 255) / 256, 256, 0, stream>>>(cnt, N);
    hist_kernel<<<(E + 255) / 256, 256, 0, stream>>>(dst, cnt, E);
    dinv_kernel<<<(N + 255) / 256, 256, 0, stream>>>(cnt, dinv, N);
    scan_kernel<<<1, 1024, 0, stream>>>(cnt, row_ptr, N);
    copy_int<<<(N + 255) / 256, 256, 0, stream>>>(row_ptr, cursor, N);
    fill_kernel<<<(E + 255) / 256, 256, 0, stream>>>(src, dst, dinv, cursor, col, wn, E);

    // --- t_emb = relu(t_embedding @ Wt + bt) -> H0 ---
    gemm_kernel<128><<<N / 32, 256, 0, stream>>>(temb_in, Wt, bt, nullptr, H0, N);

    // --- conv1: aggregate x (64-dim) then GEMM; h1 = relu(agg@W1+b1) + t_emb -> H1 ---
    agg64_kernel<<<N * 64 / 256, 256, 0, stream>>>(x, row_ptr, col, wn, dinv, A64, N);
    gemm_kernel<64><<<N / 32, 256, 0, stream>>>(A64, W1, b1, H0, H1, N);

    // --- conv2: aggregate H1 -> H0; h2 = relu(H0@Ws0+bs0) -> H0 (in-place) ---
    agg128_kernel<<<N * 64 / 256, 256, 0, stream>>>(H1, row_ptr, col, wn, dinv, H0, N);
    gemm_kernel<128><<<N / 32, 256, 0, stream>>>(H0, Ws, bs, nullptr, H0, N);

    // --- conv3: aggregate H0 -> H1; h3 = relu(H1@Ws1+bs1) -> H1 (in-place) ---
    agg128_kernel<<<N * 64 / 256, 256, 0, stream>>>(H0, row_ptr, col, wn, dinv, H1, N);
    gemm_kernel<128><<<N / 32, 256, 0, stream>>>(H1, Ws + 128 * 128, bs + 128, nullptr, H1, N);

    // --- pool + output head ---
    boundary_kernel<<<(N + 255) / 256, 256, 0, stream>>>(batch, gstart, N);
    pool_kernel<<<N_GRAPHS, HID, 0, stream>>>(H1, gstart, pooled);
    out_gemm_kernel<<<(N_GRAPHS * 16 + 255) / 256, 256, 0, stream>>>(pooled, Wo, bo, out);
}

// Round 2
// 811.724 us; speedup vs baseline: 1.5314x; 1.5314x over previous
//
#include <hip/hip_runtime.h>

#define N_NODES  100000
#define N_EDGES  1600000
#define N_GRAPHS 512
#define HID      128

typedef unsigned int  uint;
typedef unsigned short ushort;
typedef __attribute__((ext_vector_type(8))) short  short8;   // 8 bf16 (4 VGPRs)
typedef __attribute__((ext_vector_type(4))) float  f32x4;

__device__ inline float bflo(uint u) { return __uint_as_float(u << 16); }
__device__ inline float bfhi(uint u) { return __uint_as_float(u & 0xffff0000u); }
__device__ inline ushort f2bf(float f) {
    uint u = __float_as_uint(f);
    return (ushort)((u + 0x7fffu + ((u >> 16) & 1u)) >> 16);   // RNE
}
__device__ inline float bf2f(ushort s) { return __uint_as_float(((uint)s) << 16); }

// ---------------- CSR build ----------------

__global__ void zero_int(int* __restrict__ p, int n) {
    int i = blockIdx.x * blockDim.x + threadIdx.x;
    if (i < n) p[i] = 0;
}

__global__ void hist_kernel(const int* __restrict__ dst, int* __restrict__ cnt, int e) {
    int i = blockIdx.x * blockDim.x + threadIdx.x;
    if (i < e) atomicAdd(&cnt[dst[i]], 1);
}

__global__ void dinv_kernel(const int* __restrict__ cnt, float* __restrict__ dinv, int n) {
    int i = blockIdx.x * blockDim.x + threadIdx.x;
    if (i < n) dinv[i] = rsqrtf((float)(cnt[i] + 1));   // +1 self loop
}

__global__ void scan_kernel(const int* __restrict__ cnt, int* __restrict__ row_ptr, int n) {
    const int T = 1024;
    __shared__ int ssum[T];
    int t = threadIdx.x;
    int chunk = (n + T - 1) / T;
    int lo = t * chunk;
    int hi = lo + chunk; if (hi > n) hi = n;
    int s = 0;
    for (int i = lo; i < hi; ++i) s += cnt[i];
    ssum[t] = s;
    __syncthreads();
    for (int off = 1; off < T; off <<= 1) {
        int x = (t >= off) ? ssum[t - off] : 0;
        __syncthreads();
        ssum[t] += x;
        __syncthreads();
    }
    int run = ssum[t] - s;
    for (int i = lo; i < hi; ++i) { row_ptr[i] = run; run += cnt[i]; }
    if (t == T - 1) row_ptr[n] = ssum[T - 1];
}

__global__ void copy_int(const int* __restrict__ a, int* __restrict__ b, int n) {
    int i = blockIdx.x * blockDim.x + threadIdx.x;
    if (i < n) b[i] = a[i];
}

__global__ void fill_kernel(const int* __restrict__ src, const int* __restrict__ dst,
                            const float* __restrict__ dinv, int* __restrict__ cursor,
                            int* __restrict__ col, float* __restrict__ wn, int e) {
    int i = blockIdx.x * blockDim.x + threadIdx.x;
    if (i >= e) return;
    int s = src[i], d = dst[i];
    int pos = atomicAdd(&cursor[d], 1);
    col[pos] = s;
    wn[pos]  = dinv[s] * dinv[d];
}

// ---------------- fp32 -> bf16 convert ----------------

__global__ void cvt_bf16(const float* __restrict__ in, ushort* __restrict__ out, int n) {
    int i = (blockIdx.x * blockDim.x + threadIdx.x) * 4;
    if (i >= n) return;
    float4 f = *(const float4*)(in + i);
    uint2 o;
    o.x = (uint)f2bf(f.x) | ((uint)f2bf(f.y) << 16);
    o.y = (uint)f2bf(f.z) | ((uint)f2bf(f.w) << 16);
    *(uint2*)(out + i) = o;
}

// ---------------- weight packing to MFMA B-fragment order ----------------
// packed[p]: p = s*4096 + cb*512 + L*8 + j  ->  W[k=s*32+(L>>4)*8+j][n=cb*16+(L&15)]
__global__ void pack_w(const float* __restrict__ Wt, const float* __restrict__ W1,
                       const float* __restrict__ Ws, ushort* __restrict__ packed) {
    int tid = blockIdx.x * blockDim.x + threadIdx.x;
    if (tid >= 57344) return;
    const float* src; int p; ushort* dst;
    if (tid < 16384)      { src = Wt;            p = tid;         dst = packed; }
    else if (tid < 24576) { src = W1;            p = tid - 16384; dst = packed + 16384; }
    else if (tid < 40960) { src = Ws;            p = tid - 24576; dst = packed + 24576; }
    else                  { src = Ws + 16384;    p = tid - 40960; dst = packed + 40960; }
    int j  = p & 7;
    int L  = (p >> 3) & 63;
    int cb = (p >> 9) & 7;
    int s  = p >> 12;
    int k  = s * 32 + (L >> 4) * 8 + j;
    int n  = cb * 16 + (L & 15);
    dst[p] = f2bf(src[k * 128 + n]);
}

// ---------------- aggregation (gather, bf16 rows, fp32 accum) ----------------

__global__ void agg128_bf(const ushort* __restrict__ h, const int* __restrict__ rp,
                          const int* __restrict__ col, const float* __restrict__ wn,
                          const float* __restrict__ dinv, ushort* __restrict__ out, int n) {
    int gid  = blockIdx.x * blockDim.x + threadIdx.x;
    int v    = gid >> 6;
    int lane = gid & 63;
    if (v >= n) return;
    int s = rp[v], e = rp[v + 1];
    float dv = dinv[v];
    float w0 = dv * dv;
    uint xv = *(const uint*)(h + (size_t)v * HID + lane * 2);
    float ax = w0 * bflo(xv), ay = w0 * bfhi(xv);
    int j = s;
    for (; j + 1 < e; j += 2) {
        int u0 = col[j], u1 = col[j + 1];
        float wA = wn[j], wB = wn[j + 1];
        uint h0 = *(const uint*)(h + (size_t)u0 * HID + lane * 2);
        uint h1 = *(const uint*)(h + (size_t)u1 * HID + lane * 2);
        ax += wA * bflo(h0); ay += wA * bfhi(h0);
        ax += wB * bflo(h1); ay += wB * bfhi(h1);
    }
    if (j < e) {
        uint h0 = *(const uint*)(h + (size_t)col[j] * HID + lane * 2);
        float wA = wn[j];
        ax += wA * bflo(h0); ay += wA * bfhi(h0);
    }
    uint o = (uint)f2bf(ax) | ((uint)f2bf(ay) << 16);
    *(uint*)(out + (size_t)v * HID + lane * 2) = o;
}

// 64-dim rows: 2 nodes per wave, 32 lanes each (uint = 2 feats / lane)
__global__ void agg64_bf(const ushort* __restrict__ x, const int* __restrict__ rp,
                         const int* __restrict__ col, const float* __restrict__ wn,
                         const float* __restrict__ dinv, ushort* __restrict__ out, int n) {
    int gid  = blockIdx.x * blockDim.x + threadIdx.x;
    int pair = gid >> 6;
    int lane = gid & 63;
    int v    = pair * 2 + (lane >> 5);
    int fl   = lane & 31;
    if (v >= n) return;
    int s = rp[v], e = rp[v + 1];
    float dv = dinv[v];
    float w0 = dv * dv;
    uint xv = *(const uint*)(x + (size_t)v * 64 + fl * 2);
    float ax = w0 * bflo(xv), ay = w0 * bfhi(xv);
    int j = s;
    for (; j + 1 < e; j += 2) {
        int u0 = col[j], u1 = col[j + 1];
        float wA = wn[j], wB = wn[j + 1];
        uint h0 = *(const uint*)(x + (size_t)u0 * 64 + fl * 2);
        uint h1 = *(const uint*)(x + (size_t)u1 * 64 + fl * 2);
        ax += wA * bflo(h0); ay += wA * bfhi(h0);
        ax += wB * bflo(h1); ay += wB * bfhi(h1);
    }
    if (j < e) {
        uint h0 = *(const uint*)(x + (size_t)col[j] * 64 + fl * 2);
        float wA = wn[j];
        ax += wA * bflo(h0); ay += wA * bfhi(h0);
    }
    uint o = (uint)f2bf(ax) | ((uint)f2bf(ay) << 16);
    *(uint*)(out + (size_t)v * 64 + fl * 2) = o;
}

// ---------------- MFMA GEMM: O[n,128] = epi(A[n,K] @ W[K,128]) ----------------
// epi: y = relu(acc + bias); if ADD: y += T[row]   (all bf16 in/out, fp32 math)
// one wave per 16-row tile; W pre-packed in B-frag order; A-frags direct global.
template <int K, bool ADD>
__global__ __launch_bounds__(256)
void mfma_gemm(const ushort* __restrict__ A, const ushort* __restrict__ Wp,
               const float* __restrict__ bias, const ushort* __restrict__ T,
               ushort* __restrict__ O, int ntiles) {
    __shared__ __align__(16) ushort so[4][16 * 128];
    int wave = threadIdx.x >> 6;
    int lane = threadIdx.x & 63;
    int tile = blockIdx.x * 4 + wave;
    if (tile >= ntiles) return;
    int row0 = tile * 16;
    int m = lane & 15, q = lane >> 4;

    f32x4 acc[8];
#pragma unroll
    for (int cb = 0; cb < 8; ++cb) acc[cb] = {0.f, 0.f, 0.f, 0.f};

    const ushort* Arow = A + (size_t)(row0 + m) * K + q * 8;
    constexpr int S = K / 32;
#pragma unroll
    for (int s = 0; s < S; ++s) {
        short8 a = *(const short8*)(Arow + s * 32);
#pragma unroll
        for (int cb = 0; cb < 8; ++cb) {
            short8 b = *(const short8*)(Wp + (size_t)((s * 8 + cb) * 64 + lane) * 8);
            acc[cb] = __builtin_amdgcn_mfma_f32_16x16x32_bf16(a, b, acc[cb], 0, 0, 0);
        }
    }

    ushort* st = so[wave];
    if (ADD) {   // stage addend tile (coalesced), consumed 1:1 per lane below
#pragma unroll
        for (int i = 0; i < 4; ++i) {
            int idx = i * 64 + lane;
            *(short8*)(st + idx * 8) = *(const short8*)(T + (size_t)row0 * 128 + idx * 8);
        }
    }
    // C/D layout: col = lane&15, row = (lane>>4)*4 + r
#pragma unroll
    for (int cb = 0; cb < 8; ++cb) {
        int colc = cb * 16 + m;
        float bv = bias[colc];
#pragma unroll
        for (int r = 0; r < 4; ++r) {
            int row = q * 4 + r;
            float v = fmaxf(acc[cb][r] + bv, 0.0f);
            if (ADD) v += bf2f(st[row * 128 + colc]);
            st[row * 128 + colc] = f2bf(v);
        }
    }
    // coalesced copy-out
#pragma unroll
    for (int i = 0; i < 4; ++i) {
        int idx = i * 64 + lane;
        *(short8*)(O + (size_t)row0 * 128 + idx * 8) = *(const short8*)(st + idx * 8);
    }
}

// ---------------- pooling ----------------

__global__ void boundary_kernel(const int* __restrict__ batch, int* __restrict__ gstart, int n) {
    int i = blockIdx.x * blockDim.x + threadIdx.x;
    if (i >= n) return;
    int b = batch[i];
    int prev = (i == 0) ? -1 : batch[i - 1];
    for (int g = prev + 1; g <= b; ++g) gstart[g] = i;
    if (i == n - 1) {
        for (int g = b + 1; g <= N_GRAPHS; ++g) gstart[g] = n;
    }
}

__global__ void pool_bf(const ushort* __restrict__ h, const int* __restrict__ gstart,
                        float* __restrict__ pooled) {
    int g = blockIdx.x;
    int t = threadIdx.x;          // 256
    int f2 = t & 63;              // uint index within row (2 feats)
    int half = t >> 6;            // 4 row-strides
    int s = gstart[g], e = gstart[g + 1];
    float ax = 0.f, ay = 0.f;
    for (int i = s + half; i < e; i += 4) {
        uint u = *(const uint*)(h + (size_t)i * HID + f2 * 2);
        ax += bflo(u); ay += bfhi(u);
    }
    __shared__ float red[2][256];
    red[0][t] = ax; red[1][t] = ay;
    __syncthreads();
    if (half == 0) {
        for (int k = 1; k < 4; ++k) { ax += red[0][f2 + 64 * k]; ay += red[1][f2 + 64 * k]; }
        float c = (float)((e - s) < 1 ? 1 : (e - s));
        pooled[g * HID + f2 * 2]     = ax / c;
        pooled[g * HID + f2 * 2 + 1] = ay / c;
    }
}

__global__ void out_gemm_kernel(const float* __restrict__ pooled, const float* __restrict__ Wo,
                                const float* __restrict__ bo, float* __restrict__ out) {
    int idx = blockIdx.x * blockDim.x + threadIdx.x;
    if (idx >= N_GRAPHS * 16) return;
    int g = idx >> 4, tgt = idx & 15;
    float acc = bo[tgt];
    for (int k = 0; k < HID; ++k) acc += pooled[g * HID + k] * Wo[k * 16 + tgt];
    out[idx] = acc;
}

// ---------------- launch ----------------

extern "C" void kernel_launch(void* const* d_in, const int* in_sizes, int n_in,
                              void* d_out, int out_size, void* d_ws, size_t ws_size,
                              hipStream_t stream) {
    const float* x       = (const float*)d_in[0];
    const int*   ei      = (const int*)d_in[1];
    const float* temb_in = (const float*)d_in[2];
    const int*   batch   = (const int*)d_in[3];
    const float* Wt      = (const float*)d_in[4];
    const float* bt      = (const float*)d_in[5];
    const float* W1      = (const float*)d_in[6];
    const float* b1      = (const float*)d_in[7];
    const float* Ws      = (const float*)d_in[8];
    const float* bs      = (const float*)d_in[9];
    const float* Wo      = (const float*)d_in[10];
    const float* bo      = (const float*)d_in[11];
    float* out = (float*)d_out;

    const int N = N_NODES, E = N_EDGES;
    const int* src = ei;
    const int* dst = ei + E;

    char* p = (char*)d_ws;
    auto carve = [&](size_t bytes) -> void* {
        void* r = (void*)p;
        p += (bytes + 255) & ~(size_t)255;
        return r;
    };
    int*    cnt     = (int*)carve((size_t)N * 4);
    float*  dinv    = (float*)carve((size_t)N * 4);
    int*    row_ptr = (int*)carve((size_t)(N + 1) * 4);
    int*    cursor  = (int*)carve((size_t)N * 4);
    int*    col     = (int*)carve((size_t)E * 4);
    float*  wn      = (float*)carve((size_t)E * 4);
    int*    gstart  = (int*)carve((size_t)(N_GRAPHS + 1) * 4);
    float*  pooled  = (float*)carve((size_t)N_GRAPHS * HID * 4);
    ushort* packed  = (ushort*)carve((size_t)57344 * 2);
    ushort* xb      = (ushort*)carve((size_t)N * 64 * 2);
    ushort* tembb   = (ushort*)carve((size_t)N * 128 * 2);  // reused as A2
    ushort* Tb      = (ushort*)carve((size_t)N * 128 * 2);  // reused as A3
    ushort* A1      = (ushort*)carve((size_t)N * 64 * 2);
    ushort* H1      = (ushort*)carve((size_t)N * 128 * 2);  // reused as H3
    ushort* H2      = (ushort*)carve((size_t)N * 128 * 2);

    const ushort* Wtp  = packed;
    const ushort* W1p  = packed + 16384;
    const ushort* Ws0p = packed + 24576;
    const ushort* Ws1p = packed + 40960;

    const int ntiles = N / 16;            // 6250
    const int gblk   = (ntiles + 3) / 4;  // 1563

    // CSR build
    zero_int<<<(N + 255) / 256, 256, 0, stream>>>(cnt, N);
    hist_kernel<<<(E + 255) / 256, 256, 0, stream>>>(dst, cnt, E);
    dinv_kernel<<<(N + 255) / 256, 256, 0, stream>>>(cnt, dinv, N);
    scan_kernel<<<1, 1024, 0, stream>>>(cnt, row_ptr, N);
    copy_int<<<(N + 255) / 256, 256, 0, stream>>>(row_ptr, cursor, N);
    fill_kernel<<<(E + 255) / 256, 256, 0, stream>>>(src, dst, dinv, cursor, col, wn, E);

    // converts + weight pack
    cvt_bf16<<<(N * 64 / 4 + 255) / 256, 256, 0, stream>>>(x, xb, N * 64);
    cvt_bf16<<<(N * 128 / 4 + 255) / 256, 256, 0, stream>>>(temb_in, tembb, N * 128);
    pack_w<<<(57344 + 255) / 256, 256, 0, stream>>>(Wt, W1, Ws, packed);

    // T = relu(temb @ Wt + bt)
    mfma_gemm<128, false><<<gblk, 256, 0, stream>>>(tembb, Wtp, bt, nullptr, Tb, ntiles);

    // conv1: agg(x) -> A1; H1 = relu(A1@W1+b1) + T
    agg64_bf<<<N / 2 * 64 / 256, 256, 0, stream>>>(xb, row_ptr, col, wn, dinv, A1, N);
    mfma_gemm<64, true><<<gblk, 256, 0, stream>>>(A1, W1p, b1, Tb, H1, ntiles);

    // conv2: agg(H1) -> A2 (=tembb space); H2 = relu(A2@Ws0+bs0)
    agg128_bf<<<N * 64 / 256, 256, 0, stream>>>(H1, row_ptr, col, wn, dinv, tembb, N);
    mfma_gemm<128, false><<<gblk, 256, 0, stream>>>(tembb, Ws0p, bs, nullptr, H2, ntiles);

    // conv3: agg(H2) -> A3 (=Tb space); H3 (=H1 space) = relu(A3@Ws1+bs1)
    agg128_bf<<<N * 64 / 256, 256, 0, stream>>>(H2, row_ptr, col, wn, dinv, Tb, N);
    mfma_gemm<128, false><<<gblk, 256, 0, stream>>>(Tb, Ws1p, bs + 128, nullptr, H1, ntiles);

    // pool + head
    boundary_kernel<<<(N + 255) / 256, 256, 0, stream>>>(batch, gstart, N);
    pool_bf<<<N_GRAPHS, 256, 0, stream>>>(H1, gstart, pooled);
    out_gemm_kernel<<<(N_GRAPHS * 16 + 255) / 256, 256, 0, stream>>>(pooled, Wo, bo, out);
}

// Round 3
// 635.112 us; speedup vs baseline: 1.9572x; 1.2781x over previous
//
#include <hip/hip_runtime.h>

#define N_NODES  100000
#define N_EDGES  1600000
#define N_GRAPHS 512
#define HID      128

typedef unsigned int  uint;
typedef unsigned short ushort;
typedef __attribute__((ext_vector_type(8))) short  short8;   // 8 bf16 (4 VGPRs)
typedef __attribute__((ext_vector_type(4))) float  f32x4;

__device__ inline float bflo(uint u) { return __uint_as_float(u << 16); }
__device__ inline float bfhi(uint u) { return __uint_as_float(u & 0xffff0000u); }
__device__ inline ushort f2bf(float f) {
    uint u = __float_as_uint(f);
    return (ushort)((u + 0x7fffu + ((u >> 16) & 1u)) >> 16);   // RNE
}
__device__ inline float bf2f(ushort s) { return __uint_as_float(((uint)s) << 16); }

// ---------------- CSR build ----------------

__global__ void zero_int(int* __restrict__ p, int n) {
    int i = blockIdx.x * blockDim.x + threadIdx.x;
    if (i < n) p[i] = 0;
}

__global__ void hist_kernel(const int* __restrict__ dst, int* __restrict__ cnt, int e) {
    int i = blockIdx.x * blockDim.x + threadIdx.x;
    if (i < e) atomicAdd(&cnt[dst[i]], 1);
}

__global__ void dinv_kernel(const int* __restrict__ cnt, float* __restrict__ dinv, int n) {
    int i = blockIdx.x * blockDim.x + threadIdx.x;
    if (i < n) dinv[i] = rsqrtf((float)(cnt[i] + 1));   // +1 self loop
}

// 3-phase parallel exclusive scan over cnt[0..n) -> row_ptr (and cursor)
// phase A: per-block (1024 elems) local exclusive scan + block totals
__global__ __launch_bounds__(256)
void scanA(const int* __restrict__ cnt, int* __restrict__ row_ptr,
           int* __restrict__ partial, int n) {
    __shared__ int ssum[256];
    int t = threadIdx.x;
    int base = blockIdx.x * 1024 + t * 4;
    int v0 = 0, v1 = 0, v2 = 0, v3 = 0;
    if (base     < n) v0 = cnt[base];
    if (base + 1 < n) v1 = cnt[base + 1];
    if (base + 2 < n) v2 = cnt[base + 2];
    if (base + 3 < n) v3 = cnt[base + 3];
    int tot = v0 + v1 + v2 + v3;
    ssum[t] = tot;
    __syncthreads();
    for (int off = 1; off < 256; off <<= 1) {
        int x = (t >= off) ? ssum[t - off] : 0;
        __syncthreads();
        ssum[t] += x;
        __syncthreads();
    }
    int excl = ssum[t] - tot;
    if (base     < n) row_ptr[base]     = excl;
    if (base + 1 < n) row_ptr[base + 1] = excl + v0;
    if (base + 2 < n) row_ptr[base + 2] = excl + v0 + v1;
    if (base + 3 < n) row_ptr[base + 3] = excl + v0 + v1 + v2;
    if (t == 255) partial[blockIdx.x] = ssum[255];
}

// phase B: scan the (<=128) block totals in one small block
__global__ void scanB(int* __restrict__ partial, int nb, int* __restrict__ row_ptr_N) {
    __shared__ int ssum[128];
    int t = threadIdx.x;
    int v = (t < nb) ? partial[t] : 0;
    ssum[t] = v;
    __syncthreads();
    for (int off = 1; off < 128; off <<= 1) {
        int x = (t >= off) ? ssum[t - off] : 0;
        __syncthreads();
        ssum[t] += x;
        __syncthreads();
    }
    if (t < nb) partial[t] = ssum[t] - v;   // exclusive
    if (t == nb - 1) *row_ptr_N = ssum[t];  // total = E
}

// phase C: add block offsets; also init cursor
__global__ void scanC(int* __restrict__ row_ptr, const int* __restrict__ partial,
                      int* __restrict__ cursor, int n) {
    int i = blockIdx.x * blockDim.x + threadIdx.x;
    if (i >= n) return;
    int v = row_ptr[i] + partial[i >> 10];
    row_ptr[i] = v;
    cursor[i]  = v;
}

// interleaved edge record: {src, bits(norm)}
__global__ void fill_kernel(const int* __restrict__ src, const int* __restrict__ dst,
                            const float* __restrict__ dinv, int* __restrict__ cursor,
                            int2* __restrict__ edge, int e) {
    int i = blockIdx.x * blockDim.x + threadIdx.x;
    if (i >= e) return;
    int s = src[i], d = dst[i];
    int pos = atomicAdd(&cursor[d], 1);
    int2 ed; ed.x = s; ed.y = __float_as_int(dinv[s] * dinv[d]);
    edge[pos] = ed;
}

// ---------------- fp32 -> bf16 convert ----------------

__global__ void cvt_bf16(const float* __restrict__ in, ushort* __restrict__ out, int n) {
    int i = (blockIdx.x * blockDim.x + threadIdx.x) * 4;
    if (i >= n) return;
    float4 f = *(const float4*)(in + i);
    uint2 o;
    o.x = (uint)f2bf(f.x) | ((uint)f2bf(f.y) << 16);
    o.y = (uint)f2bf(f.z) | ((uint)f2bf(f.w) << 16);
    *(uint2*)(out + i) = o;
}

// ---------------- weight packing to MFMA B-fragment order ----------------
__global__ void pack_w(const float* __restrict__ Wt, const float* __restrict__ W1,
                       const float* __restrict__ Ws, ushort* __restrict__ packed) {
    int tid = blockIdx.x * blockDim.x + threadIdx.x;
    if (tid >= 57344) return;
    const float* src; int p; ushort* dst;
    if (tid < 16384)      { src = Wt;            p = tid;         dst = packed; }
    else if (tid < 24576) { src = W1;            p = tid - 16384; dst = packed + 16384; }
    else if (tid < 40960) { src = Ws;            p = tid - 24576; dst = packed + 24576; }
    else                  { src = Ws + 16384;    p = tid - 40960; dst = packed + 40960; }
    int j  = p & 7;
    int L  = (p >> 3) & 63;
    int cb = (p >> 9) & 7;
    int s  = p >> 12;
    int k  = s * 32 + (L >> 4) * 8 + j;
    int n  = cb * 16 + (L & 15);
    dst[p] = f2bf(src[k * 128 + n]);
}

// ---------------- aggregation (gather, bf16 rows, fp32 accum) ----------------
// agg128: one wave per node; half-waves own alternating edges; uint2 = 4 feats/lane.
__global__ void agg128_bf(const ushort* __restrict__ h, const int* __restrict__ rp,
                          const int2* __restrict__ edge, const float* __restrict__ dinv,
                          ushort* __restrict__ out, int n) {
    int gid  = blockIdx.x * blockDim.x + threadIdx.x;
    int v    = gid >> 6;
    int lane = gid & 63;
    if (v >= n) return;
    int half = lane >> 5, fl = lane & 31;
    int s = rp[v], e = rp[v + 1];
    float4 acc = {0.f, 0.f, 0.f, 0.f};
    if (half == 0) {
        uint2 xv = *(const uint2*)(h + (size_t)v * HID + fl * 4);
        float dv = dinv[v]; float w0 = dv * dv;
        acc.x = w0 * bflo(xv.x); acc.y = w0 * bfhi(xv.x);
        acc.z = w0 * bflo(xv.y); acc.w = w0 * bfhi(xv.y);
    }
    int iters = (e - s + 1) >> 1;
    int j = s + half;
    for (int i = 0; i < iters; ++i, j += 2) {
        int jj = (j < e) ? j : e - 1;       // safe: iters>0 => e-1 >= s
        int2 ed = edge[jj];
        float w = (j < e) ? __int_as_float(ed.y) : 0.0f;
        uint2 hv = *(const uint2*)(h + (size_t)ed.x * HID + fl * 4);
        acc.x += w * bflo(hv.x); acc.y += w * bfhi(hv.x);
        acc.z += w * bflo(hv.y); acc.w += w * bfhi(hv.y);
    }
    acc.x += __shfl_xor(acc.x, 32);
    acc.y += __shfl_xor(acc.y, 32);
    acc.z += __shfl_xor(acc.z, 32);
    acc.w += __shfl_xor(acc.w, 32);
    if (half == 0) {
        uint2 o;
        o.x = (uint)f2bf(acc.x) | ((uint)f2bf(acc.y) << 16);
        o.y = (uint)f2bf(acc.z) | ((uint)f2bf(acc.w) << 16);
        *(uint2*)(out + (size_t)v * HID + fl * 4) = o;
    }
}

// agg64: one wave per node; quarter-waves own 4 consecutive edges; uint2 = 4 feats/lane (16 lanes/row).
__global__ void agg64_bf(const ushort* __restrict__ x, const int* __restrict__ rp,
                         const int2* __restrict__ edge, const float* __restrict__ dinv,
                         ushort* __restrict__ out, int n) {
    int gid  = blockIdx.x * blockDim.x + threadIdx.x;
    int v    = gid >> 6;
    int lane = gid & 63;
    if (v >= n) return;
    int quad = lane >> 4, fq = lane & 15;
    int s = rp[v], e = rp[v + 1];
    float4 acc = {0.f, 0.f, 0.f, 0.f};
    if (quad == 0) {
        uint2 xv = *(const uint2*)(x + (size_t)v * 64 + fq * 4);
        float dv = dinv[v]; float w0 = dv * dv;
        acc.x = w0 * bflo(xv.x); acc.y = w0 * bfhi(xv.x);
        acc.z = w0 * bflo(xv.y); acc.w = w0 * bfhi(xv.y);
    }
    int iters = (e - s + 3) >> 2;
    int j = s + quad;
    for (int i = 0; i < iters; ++i, j += 4) {
        int jj = (j < e) ? j : e - 1;
        int2 ed = edge[jj];
        float w = (j < e) ? __int_as_float(ed.y) : 0.0f;
        uint2 hv = *(const uint2*)(x + (size_t)ed.x * 64 + fq * 4);
        acc.x += w * bflo(hv.x); acc.y += w * bfhi(hv.x);
        acc.z += w * bflo(hv.y); acc.w += w * bfhi(hv.y);
    }
    acc.x += __shfl_xor(acc.x, 16); acc.y += __shfl_xor(acc.y, 16);
    acc.z += __shfl_xor(acc.z, 16); acc.w += __shfl_xor(acc.w, 16);
    acc.x += __shfl_xor(acc.x, 32); acc.y += __shfl_xor(acc.y, 32);
    acc.z += __shfl_xor(acc.z, 32); acc.w += __shfl_xor(acc.w, 32);
    if (quad == 0) {
        uint2 o;
        o.x = (uint)f2bf(acc.x) | ((uint)f2bf(acc.y) << 16);
        o.y = (uint)f2bf(acc.z) | ((uint)f2bf(acc.w) << 16);
        *(uint2*)(out + (size_t)v * 64 + fq * 4) = o;
    }
}

// ---------------- MFMA GEMM: O[n,128] = epi(A[n,K] @ W[K,128]) ----------------
template <int K, bool ADD>
__global__ __launch_bounds__(256)
void mfma_gemm(const ushort* __restrict__ A, const ushort* __restrict__ Wp,
               const float* __restrict__ bias, const ushort* __restrict__ T,
               ushort* __restrict__ O, int ntiles) {
    __shared__ __align__(16) ushort so[4][16 * 128];
    int wave = threadIdx.x >> 6;
    int lane = threadIdx.x & 63;
    int tile = blockIdx.x * 4 + wave;
    if (tile >= ntiles) return;
    int row0 = tile * 16;
    int m = lane & 15, q = lane >> 4;

    f32x4 acc[8];
#pragma unroll
    for (int cb = 0; cb < 8; ++cb) acc[cb] = {0.f, 0.f, 0.f, 0.f};

    const ushort* Arow = A + (size_t)(row0 + m) * K + q * 8;
    constexpr int S = K / 32;
#pragma unroll
    for (int s = 0; s < S; ++s) {
        short8 a = *(const short8*)(Arow + s * 32);
#pragma unroll
        for (int cb = 0; cb < 8; ++cb) {
            short8 b = *(const short8*)(Wp + (size_t)((s * 8 + cb) * 64 + lane) * 8);
            acc[cb] = __builtin_amdgcn_mfma_f32_16x16x32_bf16(a, b, acc[cb], 0, 0, 0);
        }
    }

    ushort* st = so[wave];
    if (ADD) {
#pragma unroll
        for (int i = 0; i < 4; ++i) {
            int idx = i * 64 + lane;
            *(short8*)(st + idx * 8) = *(const short8*)(T + (size_t)row0 * 128 + idx * 8);
        }
    }
    // C/D layout: col = lane&15, row = (lane>>4)*4 + r
#pragma unroll
    for (int cb = 0; cb < 8; ++cb) {
        int colc = cb * 16 + m;
        float bv = bias[colc];
#pragma unroll
        for (int r = 0; r < 4; ++r) {
            int row = q * 4 + r;
            float v = fmaxf(acc[cb][r] + bv, 0.0f);
            if (ADD) v += bf2f(st[row * 128 + colc]);
            st[row * 128 + colc] = f2bf(v);
        }
    }
#pragma unroll
    for (int i = 0; i < 4; ++i) {
        int idx = i * 64 + lane;
        *(short8*)(O + (size_t)row0 * 128 + idx * 8) = *(const short8*)(st + idx * 8);
    }
}

// ---------------- pooling ----------------

__global__ void boundary_kernel(const int* __restrict__ batch, int* __restrict__ gstart, int n) {
    int i = blockIdx.x * blockDim.x + threadIdx.x;
    if (i >= n) return;
    int b = batch[i];
    int prev = (i == 0) ? -1 : batch[i - 1];
    for (int g = prev + 1; g <= b; ++g) gstart[g] = i;
    if (i == n - 1) {
        for (int g = b + 1; g <= N_GRAPHS; ++g) gstart[g] = n;
    }
}

__global__ void pool_bf(const ushort* __restrict__ h, const int* __restrict__ gstart,
                        float* __restrict__ pooled) {
    int g = blockIdx.x;
    int t = threadIdx.x;          // 256
    int f2 = t & 63;
    int half = t >> 6;
    int s = gstart[g], e = gstart[g + 1];
    float ax = 0.f, ay = 0.f;
    for (int i = s + half; i < e; i += 4) {
        uint u = *(const uint*)(h + (size_t)i * HID + f2 * 2);
        ax += bflo(u); ay += bfhi(u);
    }
    __shared__ float red[2][256];
    red[0][t] = ax; red[1][t] = ay;
    __syncthreads();
    if (half == 0) {
        for (int k = 1; k < 4; ++k) { ax += red[0][f2 + 64 * k]; ay += red[1][f2 + 64 * k]; }
        float c = (float)((e - s) < 1 ? 1 : (e - s));
        pooled[g * HID + f2 * 2]     = ax / c;
        pooled[g * HID + f2 * 2 + 1] = ay / c;
    }
}

__global__ void out_gemm_kernel(const float* __restrict__ pooled, const float* __restrict__ Wo,
                                const float* __restrict__ bo, float* __restrict__ out) {
    int idx = blockIdx.x * blockDim.x + threadIdx.x;
    if (idx >= N_GRAPHS * 16) return;
    int g = idx >> 4, tgt = idx & 15;
    float acc = bo[tgt];
    for (int k = 0; k < HID; ++k) acc += pooled[g * HID + k] * Wo[k * 16 + tgt];
    out[idx] = acc;
}

// ---------------- launch ----------------

extern "C" void kernel_launch(void* const* d_in, const int* in_sizes, int n_in,
                              void* d_out, int out_size, void* d_ws, size_t ws_size,
                              hipStream_t stream) {
    const float* x       = (const float*)d_in[0];
    const int*   ei      = (const int*)d_in[1];
    const float* temb_in = (const float*)d_in[2];
    const int*   batch   = (const int*)d_in[3];
    const float* Wt      = (const float*)d_in[4];
    const float* bt      = (const float*)d_in[5];
    const float* W1      = (const float*)d_in[6];
    const float* b1      = (const float*)d_in[7];
    const float* Ws      = (const float*)d_in[8];
    const float* bs      = (const float*)d_in[9];
    const float* Wo      = (const float*)d_in[10];
    const float* bo      = (const float*)d_in[11];
    float* out = (float*)d_out;

    const int N = N_NODES, E = N_EDGES;
    const int* src = ei;
    const int* dst = ei + E;

    char* p = (char*)d_ws;
    auto carve = [&](size_t bytes) -> void* {
        void* r = (void*)p;
        p += (bytes + 255) & ~(size_t)255;
        return r;
    };
    int*    cnt     = (int*)carve((size_t)N * 4);
    float*  dinv    = (float*)carve((size_t)N * 4);
    int*    row_ptr = (int*)carve((size_t)(N + 1) * 4);
    int*    cursor  = (int*)carve((size_t)N * 4);
    int*    partial = (int*)carve((size_t)128 * 4);
    int2*   edge    = (int2*)carve((size_t)E * 8);
    int*    gstart  = (int*)carve((size_t)(N_GRAPHS + 1) * 4);
    float*  pooled  = (float*)carve((size_t)N_GRAPHS * HID * 4);
    ushort* packed  = (ushort*)carve((size_t)57344 * 2);
    ushort* xb      = (ushort*)carve((size_t)N * 64 * 2);
    ushort* tembb   = (ushort*)carve((size_t)N * 128 * 2);  // reused as A2
    ushort* Tb      = (ushort*)carve((size_t)N * 128 * 2);  // reused as A3
    ushort* A1      = (ushort*)carve((size_t)N * 64 * 2);
    ushort* H1      = (ushort*)carve((size_t)N * 128 * 2);  // reused as H3
    ushort* H2      = (ushort*)carve((size_t)N * 128 * 2);

    const ushort* Wtp  = packed;
    const ushort* W1p  = packed + 16384;
    const ushort* Ws0p = packed + 24576;
    const ushort* Ws1p = packed + 40960;

    const int ntiles = N / 16;            // 6250
    const int gblk   = (ntiles + 3) / 4;  // 1563
    const int nb     = (N + 1023) / 1024; // 98 scan blocks

    // CSR build
    zero_int<<<(N + 255) / 256, 256, 0, stream>>>(cnt, N);
    hist_kernel<<<(E + 255) / 256, 256, 0, stream>>>(dst, cnt, E);
    dinv_kernel<<<(N + 255) / 256, 256, 0, stream>>>(cnt, dinv, N);
    scanA<<<nb, 256, 0, stream>>>(cnt, row_ptr, partial, N);
    scanB<<<1, 128, 0, stream>>>(partial, nb, row_ptr + N);
    scanC<<<(N + 255) / 256, 256, 0, stream>>>(row_ptr, partial, cursor, N);
    fill_kernel<<<(E + 255) / 256, 256, 0, stream>>>(src, dst, dinv, cursor, edge, E);

    // converts + weight pack
    cvt_bf16<<<(N * 64 / 4 + 255) / 256, 256, 0, stream>>>(x, xb, N * 64);
    cvt_bf16<<<(N * 128 / 4 + 255) / 256, 256, 0, stream>>>(temb_in, tembb, N * 128);
    pack_w<<<(57344 + 255) / 256, 256, 0, stream>>>(Wt, W1, Ws, packed);

    // T = relu(temb @ Wt + bt)
    mfma_gemm<128, false><<<gblk, 256, 0, stream>>>(tembb, Wtp, bt, nullptr, Tb, ntiles);

    // conv1: agg(x) -> A1; H1 = relu(A1@W1+b1) + T
    agg64_bf<<<(N * 64 + 255) / 256, 256, 0, stream>>>(xb, row_ptr, edge, dinv, A1, N);
    mfma_gemm<64, true><<<gblk, 256, 0, stream>>>(A1, W1p, b1, Tb, H1, ntiles);

    // conv2: agg(H1) -> A2 (=tembb space); H2 = relu(A2@Ws0+bs0)
    agg128_bf<<<(N * 64 + 255) / 256, 256, 0, stream>>>(H1, row_ptr, edge, dinv, tembb, N);
    mfma_gemm<128, false><<<gblk, 256, 0, stream>>>(tembb, Ws0p, bs, nullptr, H2, ntiles);

    // conv3: agg(H2) -> A3 (=Tb space); H3 (=H1 space) = relu(A3@Ws1+bs1)
    agg128_bf<<<(N * 64 + 255) / 256, 256, 0, stream>>>(H2, row_ptr, edge, dinv, Tb, N);
    mfma_gemm<128, false><<<gblk, 256, 0, stream>>>(Tb, Ws1p, bs + 128, nullptr, H1, ntiles);

    // pool + head
    boundary_kernel<<<(N + 255) / 256, 256, 0, stream>>>(batch, gstart, N);
    pool_bf<<<N_GRAPHS, 256, 0, stream>>>(H1, gstart, pooled);
    out_gemm_kernel<<<(N_GRAPHS * 16 + 255) / 256, 256, 0, stream>>>(pooled, Wo, bo, out);
}

// Round 4
// 588.715 us; speedup vs baseline: 2.1115x; 1.0788x over previous
//
#include <hip/hip_runtime.h>

#define N_NODES  100000
#define N_EDGES  1600000
#define N_GRAPHS 512
#define HID      128

typedef unsigned int  uint;
typedef unsigned short ushort;
typedef __attribute__((ext_vector_type(8))) short  short8;   // 8 bf16 (4 VGPRs)
typedef __attribute__((ext_vector_type(4))) float  f32x4;

__device__ inline float bflo(uint u) { return __uint_as_float(u << 16); }
__device__ inline float bfhi(uint u) { return __uint_as_float(u & 0xffff0000u); }
__device__ inline ushort f2bf(float f) {
    uint u = __float_as_uint(f);
    return (ushort)((u + 0x7fffu + ((u >> 16) & 1u)) >> 16);   // RNE
}
__device__ inline float bf2f(ushort s) { return __uint_as_float(((uint)s) << 16); }
__device__ inline uint pk(float a, float b) {
    return (uint)f2bf(a) | ((uint)f2bf(b) << 16);
}

// ---------------- CSR build ----------------

__global__ void zero_int(int* __restrict__ p, int n) {
    int i = blockIdx.x * blockDim.x + threadIdx.x;
    if (i < n) p[i] = 0;
}

__global__ void hist_kernel(const int* __restrict__ dst, int* __restrict__ cnt, int e) {
    int i = blockIdx.x * blockDim.x + threadIdx.x;
    if (i < e) atomicAdd(&cnt[dst[i]], 1);
}

// phase A: per-block (1024 elems) local exclusive scan + block totals; also dinv
__global__ __launch_bounds__(256)
void scanA(const int* __restrict__ cnt, int* __restrict__ row_ptr,
           int* __restrict__ partial, float* __restrict__ dinv, int n) {
    __shared__ int ssum[256];
    int t = threadIdx.x;
    int base = blockIdx.x * 1024 + t * 4;
    int v0 = 0, v1 = 0, v2 = 0, v3 = 0;
    if (base     < n) v0 = cnt[base];
    if (base + 1 < n) v1 = cnt[base + 1];
    if (base + 2 < n) v2 = cnt[base + 2];
    if (base + 3 < n) v3 = cnt[base + 3];
    if (base     < n) dinv[base]     = rsqrtf((float)(v0 + 1));
    if (base + 1 < n) dinv[base + 1] = rsqrtf((float)(v1 + 1));
    if (base + 2 < n) dinv[base + 2] = rsqrtf((float)(v2 + 1));
    if (base + 3 < n) dinv[base + 3] = rsqrtf((float)(v3 + 1));
    int tot = v0 + v1 + v2 + v3;
    ssum[t] = tot;
    __syncthreads();
    for (int off = 1; off < 256; off <<= 1) {
        int x = (t >= off) ? ssum[t - off] : 0;
        __syncthreads();
        ssum[t] += x;
        __syncthreads();
    }
    int excl = ssum[t] - tot;
    if (base     < n) row_ptr[base]     = excl;
    if (base + 1 < n) row_ptr[base + 1] = excl + v0;
    if (base + 2 < n) row_ptr[base + 2] = excl + v0 + v1;
    if (base + 3 < n) row_ptr[base + 3] = excl + v0 + v1 + v2;
    if (t == 255) partial[blockIdx.x] = ssum[255];
}

__global__ void scanB(int* __restrict__ partial, int nb, int* __restrict__ row_ptr_N) {
    __shared__ int ssum[128];
    int t = threadIdx.x;
    int v = (t < nb) ? partial[t] : 0;
    ssum[t] = v;
    __syncthreads();
    for (int off = 1; off < 128; off <<= 1) {
        int x = (t >= off) ? ssum[t - off] : 0;
        __syncthreads();
        ssum[t] += x;
        __syncthreads();
    }
    if (t < nb) partial[t] = ssum[t] - v;
    if (t == nb - 1) *row_ptr_N = ssum[t];
}

__global__ void scanC(int* __restrict__ row_ptr, const int* __restrict__ partial,
                      int* __restrict__ cursor, int n) {
    int i = blockIdx.x * blockDim.x + threadIdx.x;
    if (i >= n) return;
    int v = row_ptr[i] + partial[i >> 10];
    row_ptr[i] = v;
    cursor[i]  = v;
}

// interleaved edge record: {src, bits(norm)}
__global__ void fill_kernel(const int* __restrict__ src, const int* __restrict__ dst,
                            const float* __restrict__ dinv, int* __restrict__ cursor,
                            int2* __restrict__ edge, int e) {
    int i = blockIdx.x * blockDim.x + threadIdx.x;
    if (i >= e) return;
    int s = src[i], d = dst[i];
    int pos = atomicAdd(&cursor[d], 1);
    int2 ed; ed.x = s; ed.y = __float_as_int(dinv[s] * dinv[d]);
    edge[pos] = ed;
}

// ---------------- fp32 -> bf16 converts (x and temb in one launch) ----------------

__global__ void cvt_both(const float* __restrict__ x, const float* __restrict__ temb,
                         ushort* __restrict__ xb, ushort* __restrict__ tembb) {
    int i = (blockIdx.x * blockDim.x + threadIdx.x) * 4;
    const int NX = N_NODES * 64;
    const float* in; ushort* out; int k;
    if (i < NX) { in = x; out = xb; k = i; }
    else {
        k = i - NX;
        if (k >= N_NODES * 128) return;
        in = temb; out = tembb;
    }
    float4 f = *(const float4*)(in + k);
    uint2 o;
    o.x = pk(f.x, f.y);
    o.y = pk(f.z, f.w);
    *(uint2*)(out + k) = o;
}

// ---------------- weight packing to MFMA B-fragment order ----------------
// packed[p]: p = s*4096 + cb*512 + L*8 + j  ->  W[k=s*32+(L>>4)*8+j][n=cb*16+(L&15)]
__global__ void pack_w(const float* __restrict__ Wt, const float* __restrict__ W1,
                       const float* __restrict__ Ws, ushort* __restrict__ packed) {
    int tid = blockIdx.x * blockDim.x + threadIdx.x;
    if (tid >= 57344) return;
    const float* src; int p; ushort* dst;
    if (tid < 16384)      { src = Wt;            p = tid;         dst = packed; }
    else if (tid < 24576) { src = W1;            p = tid - 16384; dst = packed + 16384; }
    else if (tid < 40960) { src = Ws;            p = tid - 24576; dst = packed + 24576; }
    else                  { src = Ws + 16384;    p = tid - 40960; dst = packed + 40960; }
    int j  = p & 7;
    int L  = (p >> 3) & 63;
    int cb = (p >> 9) & 7;
    int s  = p >> 12;
    int k  = s * 32 + (L >> 4) * 8 + j;
    int n  = cb * 16 + (L & 15);
    dst[p] = f2bf(src[k * 128 + n]);
}

// ---------------- plain MFMA GEMM (temb layer): O = relu(A@W + b) ----------------
__global__ __launch_bounds__(256)
void mfma_gemm128(const ushort* __restrict__ A, const ushort* __restrict__ Wp,
                  const float* __restrict__ bias, ushort* __restrict__ O, int ntiles) {
    __shared__ __align__(16) ushort so[4][16 * 128];
    int wave = threadIdx.x >> 6;
    int lane = threadIdx.x & 63;
    int tile = blockIdx.x * 4 + wave;
    if (tile >= ntiles) return;
    int row0 = tile * 16;
    int m = lane & 15, q = lane >> 4;

    f32x4 acc[8];
#pragma unroll
    for (int cb = 0; cb < 8; ++cb) acc[cb] = {0.f, 0.f, 0.f, 0.f};

    const ushort* Arow = A + (size_t)(row0 + m) * 128 + q * 8;
#pragma unroll
    for (int s = 0; s < 4; ++s) {
        short8 a = *(const short8*)(Arow + s * 32);
#pragma unroll
        for (int cb = 0; cb < 8; ++cb) {
            short8 b = *(const short8*)(Wp + (size_t)((s * 8 + cb) * 64 + lane) * 8);
            acc[cb] = __builtin_amdgcn_mfma_f32_16x16x32_bf16(a, b, acc[cb], 0, 0, 0);
        }
    }
    ushort* st = so[wave];
#pragma unroll
    for (int cb = 0; cb < 8; ++cb) {
        int colc = cb * 16 + m;
        float bv = bias[colc];
#pragma unroll
        for (int r = 0; r < 4; ++r) {
            st[(q * 4 + r) * 128 + colc] = f2bf(fmaxf(acc[cb][r] + bv, 0.0f));
        }
    }
#pragma unroll
    for (int i = 0; i < 4; ++i) {
        int idx = i * 64 + lane;
        *(short8*)(O + (size_t)row0 * 128 + idx * 8) = *(const short8*)(st + idx * 8);
    }
}

// ---------------- fused GCN conv: gather(H) -> LDS -> MFMA -> epi -> O ----------------
// O[v,:] = relu( (sum_{u in N(v)} norm*H[u,:] + dinv^2*H[v,:]) @ W + b ) [+ T[v,:]]
template <int K, bool ADD>
__global__ __launch_bounds__(256)
void fused_conv(const ushort* __restrict__ H, const int* __restrict__ rp,
                const int2* __restrict__ edge, const float* __restrict__ dinv,
                const ushort* __restrict__ Wp, const float* __restrict__ bias,
                const ushort* __restrict__ T, ushort* __restrict__ O, int ntiles) {
    constexpr int LPR  = K / 8;       // lanes per gathered row (uint4 = 8 feats/lane)
    constexpr int G    = 64 / LPR;    // edge groups per wave (4 for K=128, 8 for K=64)
    constexpr int LROW = 136;         // LDS row stride in shorts (16B-aligned, padded)
    __shared__ __align__(16) ushort sA[4][16 * LROW];
    __shared__ __align__(16) ushort sT[ADD ? 4 * 16 * 128 : 4];
    const int wave = threadIdx.x >> 6;
    const int lane = threadIdx.x & 63;
    const int tile = blockIdx.x * 4 + wave;
    if (tile >= ntiles) return;       // no barriers in this kernel: safe
    const int row0 = tile * 16;
    const int g  = lane / LPR;
    const int fq = lane % LPR;
    ushort* myA = sA[wave];

    // ---- phase 1: gather 16 rows into LDS ----
    for (int r = 0; r < 16; ++r) {
        int v = row0 + r;
        int s = rp[v], e = rp[v + 1];
        float a0 = 0.f, a1 = 0.f, a2 = 0.f, a3 = 0.f;
        float a4 = 0.f, a5 = 0.f, a6 = 0.f, a7 = 0.f;
        if (g == 0) {   // self-loop term
            uint4 xv = *(const uint4*)(H + (size_t)v * K + fq * 8);
            float dv = dinv[v]; float w0 = dv * dv;
            a0 = w0 * bflo(xv.x); a1 = w0 * bfhi(xv.x);
            a2 = w0 * bflo(xv.y); a3 = w0 * bfhi(xv.y);
            a4 = w0 * bflo(xv.z); a5 = w0 * bfhi(xv.z);
            a6 = w0 * bflo(xv.w); a7 = w0 * bfhi(xv.w);
        }
        int iters = (e - s + G - 1) / G;   // wave-uniform
        int j = s + g;
        for (int i = 0; i < iters; i += 2, j += 2 * G) {
            int j0 = j, j1 = j + G;
            int jj0 = (j0 < e) ? j0 : e - 1;
            int jj1 = (j1 < e) ? j1 : e - 1;
            int2 e0 = edge[jj0];
            int2 e1 = edge[jj1];
            float w0 = (j0 < e) ? __int_as_float(e0.y) : 0.f;
            float w1 = (j1 < e) ? __int_as_float(e1.y) : 0.f;
            uint4 h0 = *(const uint4*)(H + (size_t)e0.x * K + fq * 8);
            uint4 h1 = *(const uint4*)(H + (size_t)e1.x * K + fq * 8);
            a0 += w0 * bflo(h0.x); a1 += w0 * bfhi(h0.x);
            a2 += w0 * bflo(h0.y); a3 += w0 * bfhi(h0.y);
            a4 += w0 * bflo(h0.z); a5 += w0 * bfhi(h0.z);
            a6 += w0 * bflo(h0.w); a7 += w0 * bfhi(h0.w);
            a0 += w1 * bflo(h1.x); a1 += w1 * bfhi(h1.x);
            a2 += w1 * bflo(h1.y); a3 += w1 * bfhi(h1.y);
            a4 += w1 * bflo(h1.z); a5 += w1 * bfhi(h1.z);
            a6 += w1 * bflo(h1.w); a7 += w1 * bfhi(h1.w);
        }
        // reduce across edge groups
        for (int d = LPR; d < 64; d <<= 1) {
            a0 += __shfl_xor(a0, d); a1 += __shfl_xor(a1, d);
            a2 += __shfl_xor(a2, d); a3 += __shfl_xor(a3, d);
            a4 += __shfl_xor(a4, d); a5 += __shfl_xor(a5, d);
            a6 += __shfl_xor(a6, d); a7 += __shfl_xor(a7, d);
        }
        if (g == 0) {
            uint4 o;
            o.x = pk(a0, a1); o.y = pk(a2, a3);
            o.z = pk(a4, a5); o.w = pk(a6, a7);
            *(uint4*)(myA + r * LROW + fq * 8) = o;
        }
    }

    // ---- phase 2: MFMA (A from LDS, B packed from global/L2) ----
    const int m = lane & 15, q = lane >> 4;
    f32x4 acc[8];
#pragma unroll
    for (int cb = 0; cb < 8; ++cb) acc[cb] = {0.f, 0.f, 0.f, 0.f};
    constexpr int S = K / 32;
#pragma unroll
    for (int s = 0; s < S; ++s) {
        short8 a = *(const short8*)(myA + m * LROW + s * 32 + q * 8);
#pragma unroll
        for (int cb = 0; cb < 8; ++cb) {
            short8 b = *(const short8*)(Wp + (size_t)((s * 8 + cb) * 64 + lane) * 8);
            acc[cb] = __builtin_amdgcn_mfma_f32_16x16x32_bf16(a, b, acc[cb], 0, 0, 0);
        }
    }

    // ---- phase 3: epilogue into LDS (overwrite myA), coalesced store ----
    ushort* st = ADD ? (&sT[0] + wave * 2048) : myA;
    if (ADD) {   // stage addend tile coalesced
#pragma unroll
        for (int i = 0; i < 4; ++i) {
            int idx = i * 64 + lane;
            *(short8*)(st + idx * 8) = *(const short8*)(T + (size_t)row0 * 128 + idx * 8);
        }
    }
    const int OST = ADD ? 128 : LROW;   // epilogue staging stride
#pragma unroll
    for (int cb = 0; cb < 8; ++cb) {
        int colc = cb * 16 + m;
        float bv = bias[colc];
#pragma unroll
        for (int r = 0; r < 4; ++r) {
            int row = q * 4 + r;
            float v = fmaxf(acc[cb][r] + bv, 0.0f);
            if (ADD) v += bf2f(st[row * 128 + colc]);
            st[row * OST + colc] = f2bf(v);
        }
    }
#pragma unroll
    for (int i = 0; i < 4; ++i) {
        int srow = i * 4 + (lane >> 4);
        int scol = (lane & 15) * 8;
        *(short8*)(O + (size_t)(row0 + srow) * 128 + scol) =
            *(const short8*)(st + srow * OST + scol);
    }
}

// ---------------- pooling ----------------

__global__ void boundary_kernel(const int* __restrict__ batch, int* __restrict__ gstart, int n) {
    int i = blockIdx.x * blockDim.x + threadIdx.x;
    if (i >= n) return;
    int b = batch[i];
    int prev = (i == 0) ? -1 : batch[i - 1];
    for (int g = prev + 1; g <= b; ++g) gstart[g] = i;
    if (i == n - 1) {
        for (int g = b + 1; g <= N_GRAPHS; ++g) gstart[g] = n;
    }
}

__global__ void pool_bf(const ushort* __restrict__ h, const int* __restrict__ gstart,
                        float* __restrict__ pooled) {
    int g = blockIdx.x;
    int t = threadIdx.x;          // 256
    int f2 = t & 63;
    int half = t >> 6;
    int s = gstart[g], e = gstart[g + 1];
    float ax = 0.f, ay = 0.f;
    for (int i = s + half; i < e; i += 4) {
        uint u = *(const uint*)(h + (size_t)i * HID + f2 * 2);
        ax += bflo(u); ay += bfhi(u);
    }
    __shared__ float red[2][256];
    red[0][t] = ax; red[1][t] = ay;
    __syncthreads();
    if (half == 0) {
        for (int k = 1; k < 4; ++k) { ax += red[0][f2 + 64 * k]; ay += red[1][f2 + 64 * k]; }
        float c = (float)((e - s) < 1 ? 1 : (e - s));
        pooled[g * HID + f2 * 2]     = ax / c;
        pooled[g * HID + f2 * 2 + 1] = ay / c;
    }
}

__global__ void out_gemm_kernel(const float* __restrict__ pooled, const float* __restrict__ Wo,
                                const float* __restrict__ bo, float* __restrict__ out) {
    int idx = blockIdx.x * blockDim.x + threadIdx.x;
    if (idx >= N_GRAPHS * 16) return;
    int g = idx >> 4, tgt = idx & 15;
    float acc = bo[tgt];
    for (int k = 0; k < HID; ++k) acc += pooled[g * HID + k] * Wo[k * 16 + tgt];
    out[idx] = acc;
}

// ---------------- launch ----------------

extern "C" void kernel_launch(void* const* d_in, const int* in_sizes, int n_in,
                              void* d_out, int out_size, void* d_ws, size_t ws_size,
                              hipStream_t stream) {
    const float* x       = (const float*)d_in[0];
    const int*   ei      = (const int*)d_in[1];
    const float* temb_in = (const float*)d_in[2];
    const int*   batch   = (const int*)d_in[3];
    const float* Wt      = (const float*)d_in[4];
    const float* bt      = (const float*)d_in[5];
    const float* W1      = (const float*)d_in[6];
    const float* b1      = (const float*)d_in[7];
    const float* Ws      = (const float*)d_in[8];
    const float* bs      = (const float*)d_in[9];
    const float* Wo      = (const float*)d_in[10];
    const float* bo      = (const float*)d_in[11];
    float* out = (float*)d_out;

    const int N = N_NODES, E = N_EDGES;
    const int* src = ei;
    const int* dst = ei + E;

    char* p = (char*)d_ws;
    auto carve = [&](size_t bytes) -> void* {
        void* r = (void*)p;
        p += (bytes + 255) & ~(size_t)255;
        return r;
    };
    int*    cnt     = (int*)carve((size_t)N * 4);
    float*  dinv    = (float*)carve((size_t)N * 4);
    int*    row_ptr = (int*)carve((size_t)(N + 1) * 4);
    int*    cursor  = (int*)carve((size_t)N * 4);
    int*    partial = (int*)carve((size_t)128 * 4);
    int2*   edge    = (int2*)carve((size_t)E * 8);
    int*    gstart  = (int*)carve((size_t)(N_GRAPHS + 1) * 4);
    float*  pooled  = (float*)carve((size_t)N_GRAPHS * HID * 4);
    ushort* packed  = (ushort*)carve((size_t)57344 * 2);
    ushort* xb      = (ushort*)carve((size_t)N * 64 * 2);
    ushort* tembb   = (ushort*)carve((size_t)N * 128 * 2);
    ushort* Tb      = (ushort*)carve((size_t)N * 128 * 2);
    ushort* H1      = (ushort*)carve((size_t)N * 128 * 2);  // also holds H3
    ushort* H2      = (ushort*)carve((size_t)N * 128 * 2);

    const ushort* Wtp  = packed;
    const ushort* W1p  = packed + 16384;
    const ushort* Ws0p = packed + 24576;
    const ushort* Ws1p = packed + 40960;

    const int ntiles = N / 16;            // 6250
    const int gblk   = (ntiles + 3) / 4;  // 1563
    const int nb     = (N + 1023) / 1024; // 98

    // CSR build
    zero_int<<<(N + 255) / 256, 256, 0, stream>>>(cnt, N);
    hist_kernel<<<(E + 255) / 256, 256, 0, stream>>>(dst, cnt, E);
    scanA<<<nb, 256, 0, stream>>>(cnt, row_ptr, partial, dinv, N);
    scanB<<<1, 128, 0, stream>>>(partial, nb, row_ptr + N);
    scanC<<<(N + 255) / 256, 256, 0, stream>>>(row_ptr, partial, cursor, N);
    fill_kernel<<<(E + 255) / 256, 256, 0, stream>>>(src, dst, dinv, cursor, edge, E);

    // converts + weight pack
    cvt_both<<<(N * 192 / 4 + 255) / 256, 256, 0, stream>>>(x, temb_in, xb, tembb);
    pack_w<<<(57344 + 255) / 256, 256, 0, stream>>>(Wt, W1, Ws, packed);

    // T = relu(temb @ Wt + bt)
    mfma_gemm128<<<gblk, 256, 0, stream>>>(tembb, Wtp, bt, Tb, ntiles);

    // conv1: H1 = relu(agg(x)@W1 + b1) + T
    fused_conv<64, true><<<gblk, 256, 0, stream>>>(xb, row_ptr, edge, dinv, W1p, b1, Tb, H1, ntiles);
    // conv2: H2 = relu(agg(H1)@Ws0 + bs0)
    fused_conv<128, false><<<gblk, 256, 0, stream>>>(H1, row_ptr, edge, dinv, Ws0p, bs, nullptr, H2, ntiles);
    // conv3: H3(=H1) = relu(agg(H2)@Ws1 + bs1)
    fused_conv<128, false><<<gblk, 256, 0, stream>>>(H2, row_ptr, edge, dinv, Ws1p, bs + 128, nullptr, H1, ntiles);

    // pool + head
    boundary_kernel<<<(N + 255) / 256, 256, 0, stream>>>(batch, gstart, N);
    pool_bf<<<N_GRAPHS, 256, 0, stream>>>(H1, gstart, pooled);
    out_gemm_kernel<<<(N_GRAPHS * 16 + 255) / 256, 256, 0, stream>>>(pooled, Wo, bo, out);
}